// Round 7
// baseline (2996.994 us; speedup 1.0000x reference)
//
#include <hip/hip_runtime.h>
#include <hip/hip_bf16.h>

#define BB 32
#define WW 384
#define LL 512
#define ITERS 16
#define NPB (WW * LL)
#define LROWS 514            // 1 + 512 + 1 halo rows
#define RP (LROWS * 8)       // shorts per octet-plane (4112)

typedef __attribute__((ext_vector_type(8))) short bf16x8;
typedef __attribute__((ext_vector_type(4))) float f32x4;

__device__ __forceinline__ float b2f(short s) {
    unsigned u = ((unsigned)(unsigned short)s) << 16;
    float f;
    __builtin_memcpy(&f, &u, 4);
    return f;
}
__device__ __forceinline__ short f2b(float v) {
    __hip_bfloat16 h = __float2bfloat16(v);
    return *(short*)&h;
}

// ---------------------------------------------------------------- prep
// op_w [384(co)][385(ci)][3] f32 -> Wh/Wl [3][52][384][8] bf16 hi/lo
__global__ void wsplit_op(const float* __restrict__ w, short* __restrict__ wh,
                          short* __restrict__ wl) {
    int i = blockIdx.x * 256 + threadIdx.x;
    if (i >= 3 * 52 * 384 * 8) return;
    int e = i & 7, co = (i >> 3) % 384, oct = (i >> 3) / 384 % 52,
        tap = i / (8 * 384 * 52);
    int ci = oct * 8 + e;
    float v = (ci < 385) ? w[(co * 385 + ci) * 3 + tap] : 0.f;
    __hip_bfloat16 h = __float2bfloat16(v);
    wh[i] = *(short*)&h;
    wl[i] = f2b(v - __bfloat162float(h));
}

// src [CO_real][384(ci)][3] f32 -> dst [3][48][COD][8] bf16 (co>=CO_real -> 0)
__global__ void wsplit_h(const float* __restrict__ w, short* __restrict__ wh,
                         int COD, int CO_real) {
    int i = blockIdx.x * 256 + threadIdx.x;
    if (i >= 3 * 48 * COD * 8) return;
    int e = i & 7, co = (i >> 3) % COD, oct = (i >> 3) / COD % 48,
        tap = i / (8 * COD * 48);
    int ci = oct * 8 + e;
    float v = (co < CO_real) ? w[(co * 384 + ci) * 3 + tap] : 0.f;
    wh[i] = f2b(v);
}

// Zero halo rows (all buffers), install x channel (octet 48, elem 0) + zero
// pad octets 48..51 in both state ping-pong buffers.
__global__ void init_rows(const float* __restrict__ x, short* itAh, short* itAl,
                          short* itBh, short* itBl, short* a1, short* a2) {
    int row = blockIdx.x % LROWS, b = blockIdx.x / LROWS;
    int tid = threadIdx.x;
    size_t sb = (size_t)b * 52 * RP;
    if (row == 0 || row == LROWS - 1) {
        for (int i = tid; i < 52 * 8; i += 64) {
            size_t o = sb + (size_t)(i >> 3) * RP + row * 8 + (i & 7);
            itAh[o] = 0; itAl[o] = 0; itBh[o] = 0; itBl[o] = 0;
        }
        for (int i = tid; i < 48 * 8; i += 64)
            a1[(size_t)b * 48 * RP + (size_t)(i >> 3) * RP + row * 8 + (i & 7)] = 0;
        for (int i = tid; i < 32 * 8; i += 64)
            a2[(size_t)b * 32 * RP + (size_t)(i >> 3) * RP + row * 8 + (i & 7)] = 0;
    } else if (tid < 32) {
        int oct = 48 + (tid >> 3), e = tid & 7;
        short h = 0, l = 0;
        if (oct == 48 && e == 0) {
            float xv = x[b * LL + row - 1];
            __hip_bfloat16 xh = __float2bfloat16(xv);
            h = *(short*)&xh;
            l = f2b(xv - __bfloat162float(xh));
        }
        size_t o = sb + (size_t)oct * RP + row * 8 + e;
        itAh[o] = h; itAl[o] = l; itBh[o] = h; itBl[o] = l;
    }
}

__global__ void zero_part(float* part, int n) {
    int i = blockIdx.x * 256 + threadIdx.x;
    if (i < n) part[i] = 0.f;
}

// it0 = relu(conv1d(x, proj_w)) -> octet-planar hi/lo + LN stats.
__global__ __launch_bounds__(256) void proj_relu(const float* __restrict__ x,
                                                 const float* __restrict__ wp,
                                                 short* __restrict__ oh,
                                                 short* __restrict__ ol,
                                                 float* __restrict__ part) {
    int b = blockIdx.x >> 3, sl = blockIdx.x & 7;
    int tid = threadIdx.x;
    __shared__ float ws[WW * 3];
    __shared__ float xs[66];
    for (int i = tid; i < WW * 3; i += 256) ws[i] = wp[i];
    int l0 = sl * 64;
    for (int i = tid; i < 66; i += 256) {
        int l = l0 + i - 1;
        xs[i] = (l >= 0 && l < LL) ? x[b * LL + l] : 0.f;
    }
    __syncthreads();
    size_t sb = (size_t)b * 52 * RP;
    float s = 0.f, sq = 0.f;
    for (int idx = tid; idx < 64 * WW; idx += 256) {
        int lo = idx / WW, co = idx % WW;
        float v = fmaxf(ws[co * 3] * xs[lo] + ws[co * 3 + 1] * xs[lo + 1] +
                            ws[co * 3 + 2] * xs[lo + 2], 0.f);
        size_t o = sb + (size_t)(co >> 3) * RP + (l0 + lo + 1) * 8 + (co & 7);
        __hip_bfloat16 h = __float2bfloat16(v);
        oh[o] = *(short*)&h;
        ol[o] = f2b(v - __bfloat162float(h));
        s += v; sq += v * v;
    }
    #pragma unroll
    for (int off = 32; off > 0; off >>= 1) {
        s += __shfl_down(s, off);
        sq += __shfl_down(sq, off);
    }
    __shared__ float sr[8];
    int w = tid >> 6;
    if ((tid & 63) == 0) { sr[w] = s; sr[4 + w] = sq; }
    __syncthreads();
    if (tid == 0) {
        atomicAdd(&part[b * 2], sr[0] + sr[1] + sr[2] + sr[3]);
        atomicAdd(&part[b * 2 + 1], sr[4] + sr[5] + sr[6] + sr[7]);
    }
}

// ------------------------------------------------- MFMA implicit-GEMM conv
// Direct-global dataflow, octet-planar layouts: all fragment loads are
// contiguous 256B/16-lane segments; no staging, no K-loop barriers.
// Block: 2 waves K-SPLIT over one 64l x 64co tile (each wave does half the
// ci-chunks), then symmetric cross-wave LDS reduction: wave w finalizes
// m-tiles {2w, 2w+1}. Doubles waves/CU vs co-split at equal load:MFMA ratio.
// Grid: CT*256, g=bid&255 (b*8+lt) -> A-sharing blocks on same XCD.
// MODE 0: relu -> bf16 octet-planar out. MODE 1: energy epilogue + LN stats.
template <int CHUNKS, int IOCT, int OOCT, int COD, int MODE, bool SPLIT>
__global__ __launch_bounds__(128, 4) void mfma_conv(
    const short* __restrict__ inh, const short* __restrict__ inl,
    const short* __restrict__ wh, const short* __restrict__ wl,
    const float* __restrict__ part_in, float* __restrict__ part_out,
    short* __restrict__ outh, short* __restrict__ outl) {
    int bid = blockIdx.x;
    int g = bid & 255;
    int ct = bid >> 8;
    int b = g >> 3, lt = g & 7;
    int l0 = lt * 64;
    int tid = threadIdx.x;
    int lane = tid & 63;
    int w = __builtin_amdgcn_readfirstlane(tid >> 6);  // K-half
    int lane15 = lane & 15, q = lane >> 4;
    int co0 = ct * 64;
    const size_t ibase = (size_t)b * IOCT * RP;

    f32x4 acc[4][4];
    #pragma unroll
    for (int i = 0; i < 4; i++)
        #pragma unroll
        for (int j = 0; j < 4; j++) acc[i][j] = (f32x4){0.f, 0.f, 0.f, 0.f};

    // lane-invariant bases
    const size_t arow = ibase + (size_t)q * RP + (l0 + lane15) * 8;
    const size_t brow = ((size_t)q * COD + co0 + lane15) * 8;

    constexpr int KB = (CHUNKS + 1) / 2;
    int kc0 = w * KB;
    int kc1 = (kc0 + KB < CHUNKS) ? kc0 + KB : CHUNKS;

    #pragma unroll 1
    for (int kc = kc0; kc < kc1; kc++) {
        #pragma unroll
        for (int tap = 0; tap < 3; tap++) {
            bf16x8 ah[4], al[4], bh[4], bl[4];
            #pragma unroll
            for (int mt = 0; mt < 4; mt++) {
                size_t ao = arow + (size_t)kc * 4 * RP + (mt * 16 + tap) * 8;
                ah[mt] = *(const bf16x8*)(inh + ao);
                if (SPLIT) al[mt] = *(const bf16x8*)(inl + ao);
            }
            #pragma unroll
            for (int nt = 0; nt < 4; nt++) {
                size_t bo = brow + ((size_t)(tap * CHUNKS + kc) * 4) * COD * 8 +
                            nt * 16 * 8;
                bh[nt] = *(const bf16x8*)(wh + bo);
                if (SPLIT) bl[nt] = *(const bf16x8*)(wl + bo);
            }
            #pragma unroll
            for (int mt = 0; mt < 4; mt++)
                #pragma unroll
                for (int nt = 0; nt < 4; nt++) {
                    acc[mt][nt] = __builtin_amdgcn_mfma_f32_16x16x32_bf16(
                        ah[mt], bh[nt], acc[mt][nt], 0, 0, 0);
                    if (SPLIT) {
                        acc[mt][nt] = __builtin_amdgcn_mfma_f32_16x16x32_bf16(
                            ah[mt], bl[nt], acc[mt][nt], 0, 0, 0);
                        acc[mt][nt] = __builtin_amdgcn_mfma_f32_16x16x32_bf16(
                            al[mt], bh[nt], acc[mt][nt], 0, 0, 0);
                    }
                }
        }
    }

    // ---- cross-wave K reduction (stride 33: conflict-free scalar f32)
    constexpr int RSTR = 33;
    __shared__ float red[2 * 64 * RSTR];
    {
        float* my = &red[w * 64 * RSTR + lane * RSTR];
        int src0 = w ? 0 : 2;  // wave w exports m-tiles it does NOT finalize
        #pragma unroll
        for (int i = 0; i < 2; i++)
            #pragma unroll
            for (int nt = 0; nt < 4; nt++)
                #pragma unroll
                for (int r = 0; r < 4; r++)
                    my[i * 16 + nt * 4 + r] = acc[src0 + i][nt][r];
    }
    __syncthreads();
    int dst0 = w ? 2 : 0;  // m-tiles this wave finalizes
    {
        const float* pr = &red[(1 - w) * 64 * RSTR + lane * RSTR];
        #pragma unroll
        for (int i = 0; i < 2; i++)
            #pragma unroll
            for (int nt = 0; nt < 4; nt++)
                #pragma unroll
                for (int r = 0; r < 4; r++)
                    acc[dst0 + i][nt][r] += pr[i * 16 + nt * 4 + r];
    }

    const size_t obase = (size_t)b * OOCT * RP;
    if (MODE == 1) {
        float s_in = part_in[b * 2], sq_in = part_in[b * 2 + 1];
        float mu = s_in / (float)NPB;
        float var = sq_in / (float)NPB - mu * mu;
        float rs = rsqrtf(var + 1e-5f);
        float s = 0.f, sq = 0.f;
        #pragma unroll
        for (int mt = dst0; mt < dst0 + 2; mt++)
            #pragma unroll
            for (int nt = 0; nt < 4; nt++)
                #pragma unroll
                for (int r = 0; r < 4; r++) {
                    int m = mt * 16 + q * 4 + r;
                    int n = co0 + nt * 16 + lane15;
                    size_t idx = ibase + (size_t)(n >> 3) * RP +
                                 (l0 + m + 1) * 8 + (n & 7);
                    float itv = b2f(inh[idx]) + b2f(inl[idx]);
                    float xl = (itv - mu) * rs;
                    float nv = xl - 0.1f * acc[mt][nt][r] - 0.2f * fmaxf(xl, 0.f);
                    s += nv;
                    sq += nv * nv;
                    __hip_bfloat16 h = __float2bfloat16(nv);
                    outh[idx] = *(short*)&h;
                    outl[idx] = f2b(nv - __bfloat162float(h));
                }
        #pragma unroll
        for (int off = 32; off > 0; off >>= 1) {
            s += __shfl_down(s, off);
            sq += __shfl_down(sq, off);
        }
        __shared__ float sr[4];
        if (lane == 0) { sr[w] = s; sr[2 + w] = sq; }
        __syncthreads();
        if (tid == 0) {
            atomicAdd(&part_out[b * 2], sr[0] + sr[1]);
            atomicAdd(&part_out[b * 2 + 1], sr[2] + sr[3]);
        }
    } else {
        #pragma unroll
        for (int mt = dst0; mt < dst0 + 2; mt++)
            #pragma unroll
            for (int nt = 0; nt < 4; nt++)
                #pragma unroll
                for (int r = 0; r < 4; r++) {
                    int m = mt * 16 + q * 4 + r;
                    int n = co0 + nt * 16 + lane15;
                    size_t idx = obase + (size_t)(n >> 3) * RP +
                                 (l0 + m + 1) * 8 + (n & 7);
                    outh[idx] = f2b(fmaxf(acc[mt][nt][r], 0.f));
                }
    }
}

// Final 192->2 conv from a2 [32][32oct][514][8] bf16 octet-planar.
__global__ __launch_bounds__(128) void h3_conv(const short* __restrict__ a2,
                                               const float* __restrict__ w3,
                                               float* __restrict__ out, int t) {
    __shared__ float ws3[2 * 192 * 3];
    int tid = threadIdx.x;
    for (int i = tid; i < 2 * 192 * 3; i += 128) ws3[i] = w3[i];
    __syncthreads();
    int b = blockIdx.x >> 3, sl = blockIdx.x & 7;
    int l = sl * 64 + (tid >> 1);
    int ch = tid & 1;
    const short* ab = a2 + (size_t)b * 32 * RP;
    const float* wc = ws3 + ch * 576;
    float a = 0.f;
    #pragma unroll 4
    for (int oct = 0; oct < 24; oct++) {
        const short* p = ab + (size_t)oct * RP + l * 8;  // row l = seq l-1
        bf16x8 v0 = *(const bf16x8*)p;
        bf16x8 v1 = *(const bf16x8*)(p + 8);
        bf16x8 v2 = *(const bf16x8*)(p + 16);
        #pragma unroll
        for (int j = 0; j < 8; j++) {
            const float* wp = wc + (oct * 8 + j) * 3;
            a += wp[0] * b2f(v0[j]) + wp[1] * b2f(v1[j]) + wp[2] * b2f(v2[j]);
        }
    }
    out[(((size_t)b * ITERS + t) * 2 + ch) * LL + l] = a;
}

extern "C" void kernel_launch(void* const* d_in, const int* in_sizes, int n_in,
                              void* d_out, int out_size, void* d_ws, size_t ws_size,
                              hipStream_t stream) {
    const float* x = (const float*)d_in[0];
    const float* proj_w = (const float*)d_in[2];
    const float* op_w = (const float*)d_in[3];
    const float* h1_w = (const float*)d_in[4];
    const float* h2_w = (const float*)d_in[5];
    const float* h3_w = (const float*)d_in[6];
    float* out = (float*)d_out;

    char* base = (char*)d_ws;
    size_t off = 0;
    auto alloc = [&](size_t bytes) {
        char* p = base + off;
        off += (bytes + 255) & ~(size_t)255;
        return p;
    };
    const size_t ITB = (size_t)BB * 52 * RP * 2;  // state buffer bytes
    short* itAh = (short*)alloc(ITB);
    short* itAl = (short*)alloc(ITB);
    short* itBh = (short*)alloc(ITB);
    short* itBl = (short*)alloc(ITB);
    short* a1 = (short*)alloc((size_t)BB * 48 * RP * 2);
    short* a2 = (short*)alloc((size_t)BB * 32 * RP * 2);
    short* wOph = (short*)alloc((size_t)3 * 52 * 384 * 8 * 2);
    short* wOpl = (short*)alloc((size_t)3 * 52 * 384 * 8 * 2);
    short* wH1 = (short*)alloc((size_t)3 * 48 * 384 * 8 * 2);
    short* wH2 = (short*)alloc((size_t)3 * 48 * 256 * 8 * 2);
    float* part = (float*)alloc((size_t)(ITERS + 1) * 64 * 4);
    if (off > ws_size) return;

    wsplit_op<<<(3 * 52 * 384 * 8 + 255) / 256, 256, 0, stream>>>(op_w, wOph, wOpl);
    wsplit_h<<<(3 * 48 * 384 * 8 + 255) / 256, 256, 0, stream>>>(h1_w, wH1, 384, 384);
    wsplit_h<<<(3 * 48 * 256 * 8 + 255) / 256, 256, 0, stream>>>(h2_w, wH2, 256, 192);
    init_rows<<<BB * LROWS, 64, 0, stream>>>(x, itAh, itAl, itBh, itBl, a1, a2);
    zero_part<<<5, 256, 0, stream>>>(part, (ITERS + 1) * 64);
    proj_relu<<<BB * 8, 256, 0, stream>>>(x, proj_w, itAh, itAl, part);

    short *ch = itAh, *cl = itAl, *nh = itBh, *nl = itBl;
    for (int t = 0; t < ITERS; t++) {
        // op conv (hi/lo split, energy epilogue): cur -> nxt, stats -> part[t+1]
        // K-split blocks: 6 co-tiles x 256 (b,lt) = 1536 blocks, 12 waves/CU
        mfma_conv<13, 52, 52, 384, 1, true><<<6 * 256, 128, 0, stream>>>(
            ch, cl, wOph, wOpl, part + t * 64, part + (t + 1) * 64, nh, nl);
        // h1: nxt_hi -> a1 (48 octets), relu
        mfma_conv<12, 52, 48, 384, 0, false><<<6 * 256, 128, 0, stream>>>(
            nh, nullptr, wH1, nullptr, nullptr, nullptr, a1, nullptr);
        // h2: a1 -> a2 (co padded to 256 -> 32 octets), relu
        mfma_conv<12, 48, 32, 256, 0, false><<<4 * 256, 128, 0, stream>>>(
            a1, nullptr, wH2, nullptr, nullptr, nullptr, a2, nullptr);
        h3_conv<<<BB * 8, 128, 0, stream>>>(a2, h3_w, out, t);
        short* th = ch; ch = nh; nh = th;
        short* tl = cl; cl = nl; nl = tl;
    }
}

// Round 8
// 2874.896 us; speedup vs baseline: 1.0425x; 1.0425x over previous
//
#include <hip/hip_runtime.h>
#include <hip/hip_bf16.h>

#define BB 32
#define WW 384
#define LL 512
#define ITERS 16
#define NPB (WW * LL)
#define LROWS 514            // 1 + 512 + 1 halo rows
#define RP (LROWS * 8)       // shorts per octet-plane (4112)

typedef __attribute__((ext_vector_type(8))) short bf16x8;
typedef __attribute__((ext_vector_type(16))) float f32x16;

__device__ __forceinline__ float b2f(short s) {
    unsigned u = ((unsigned)(unsigned short)s) << 16;
    float f;
    __builtin_memcpy(&f, &u, 4);
    return f;
}
__device__ __forceinline__ short f2b(float v) {
    __hip_bfloat16 h = __float2bfloat16(v);
    return *(short*)&h;
}

// ---------------------------------------------------------------- prep
// op_w [384(co)][385(ci)][3] f32 -> Wh/Wl [3][52][384][8] bf16 hi/lo
__global__ void wsplit_op(const float* __restrict__ w, short* __restrict__ wh,
                          short* __restrict__ wl) {
    int i = blockIdx.x * 256 + threadIdx.x;
    if (i >= 3 * 52 * 384 * 8) return;
    int e = i & 7, co = (i >> 3) % 384, oct = (i >> 3) / 384 % 52,
        tap = i / (8 * 384 * 52);
    int ci = oct * 8 + e;
    float v = (ci < 385) ? w[(co * 385 + ci) * 3 + tap] : 0.f;
    __hip_bfloat16 h = __float2bfloat16(v);
    wh[i] = *(short*)&h;
    wl[i] = f2b(v - __bfloat162float(h));
}

// src [CO_real][384(ci)][3] f32 -> dst [3][48][COD][8] bf16 (co>=CO_real -> 0)
__global__ void wsplit_h(const float* __restrict__ w, short* __restrict__ wh,
                         int COD, int CO_real) {
    int i = blockIdx.x * 256 + threadIdx.x;
    if (i >= 3 * 48 * COD * 8) return;
    int e = i & 7, co = (i >> 3) % COD, oct = (i >> 3) / COD % 48,
        tap = i / (8 * COD * 48);
    int ci = oct * 8 + e;
    float v = (co < CO_real) ? w[(co * 384 + ci) * 3 + tap] : 0.f;
    wh[i] = f2b(v);
}

// Zero halo rows (all buffers), install x channel (octet 48, elem 0) + zero
// pad octets 48..51 in both state ping-pong buffers.
__global__ void init_rows(const float* __restrict__ x, short* itAh, short* itAl,
                          short* itBh, short* itBl, short* a1, short* a2) {
    int row = blockIdx.x % LROWS, b = blockIdx.x / LROWS;
    int tid = threadIdx.x;
    size_t sb = (size_t)b * 52 * RP;
    if (row == 0 || row == LROWS - 1) {
        for (int i = tid; i < 52 * 8; i += 64) {
            size_t o = sb + (size_t)(i >> 3) * RP + row * 8 + (i & 7);
            itAh[o] = 0; itAl[o] = 0; itBh[o] = 0; itBl[o] = 0;
        }
        for (int i = tid; i < 48 * 8; i += 64)
            a1[(size_t)b * 48 * RP + (size_t)(i >> 3) * RP + row * 8 + (i & 7)] = 0;
        for (int i = tid; i < 32 * 8; i += 64)
            a2[(size_t)b * 32 * RP + (size_t)(i >> 3) * RP + row * 8 + (i & 7)] = 0;
    } else if (tid < 32) {
        int oct = 48 + (tid >> 3), e = tid & 7;
        short h = 0, l = 0;
        if (oct == 48 && e == 0) {
            float xv = x[b * LL + row - 1];
            __hip_bfloat16 xh = __float2bfloat16(xv);
            h = *(short*)&xh;
            l = f2b(xv - __bfloat162float(xh));
        }
        size_t o = sb + (size_t)oct * RP + row * 8 + e;
        itAh[o] = h; itAl[o] = l; itBh[o] = h; itBl[o] = l;
    }
}

__global__ void zero_part(float* part, int n) {
    int i = blockIdx.x * 256 + threadIdx.x;
    if (i < n) part[i] = 0.f;
}

// it0 = relu(conv1d(x, proj_w)) -> octet-planar hi/lo + LN stats.
__global__ __launch_bounds__(256) void proj_relu(const float* __restrict__ x,
                                                 const float* __restrict__ wp,
                                                 short* __restrict__ oh,
                                                 short* __restrict__ ol,
                                                 float* __restrict__ part) {
    int b = blockIdx.x >> 3, sl = blockIdx.x & 7;
    int tid = threadIdx.x;
    __shared__ float ws[WW * 3];
    __shared__ float xs[66];
    for (int i = tid; i < WW * 3; i += 256) ws[i] = wp[i];
    int l0 = sl * 64;
    for (int i = tid; i < 66; i += 256) {
        int l = l0 + i - 1;
        xs[i] = (l >= 0 && l < LL) ? x[b * LL + l] : 0.f;
    }
    __syncthreads();
    size_t sb = (size_t)b * 52 * RP;
    float s = 0.f, sq = 0.f;
    for (int idx = tid; idx < 64 * WW; idx += 256) {
        int lo = idx / WW, co = idx % WW;
        float v = fmaxf(ws[co * 3] * xs[lo] + ws[co * 3 + 1] * xs[lo + 1] +
                            ws[co * 3 + 2] * xs[lo + 2], 0.f);
        size_t o = sb + (size_t)(co >> 3) * RP + (l0 + lo + 1) * 8 + (co & 7);
        __hip_bfloat16 h = __float2bfloat16(v);
        oh[o] = *(short*)&h;
        ol[o] = f2b(v - __bfloat162float(h));
        s += v; sq += v * v;
    }
    #pragma unroll
    for (int off = 32; off > 0; off >>= 1) {
        s += __shfl_down(s, off);
        sq += __shfl_down(sq, off);
    }
    __shared__ float sr[8];
    int w = tid >> 6;
    if ((tid & 63) == 0) { sr[w] = s; sr[4 + w] = sq; }
    __syncthreads();
    if (tid == 0) {
        atomicAdd(&part[b * 2], sr[0] + sr[1] + sr[2] + sr[3]);
        atomicAdd(&part[b * 2 + 1], sr[4] + sr[5] + sr[6] + sr[7]);
    }
}

// ------------------------------------------------- MFMA implicit-GEMM conv
// 32x32x16 fragments, direct-global octet-planar loads (contiguous 512B per
// 32-lane group), register-double-buffered K-loop (loads for iter i+1 in
// flight during MFMAs of iter i -> vmcnt(8), never 0), no K-loop barriers.
// Block: 2 waves K-SPLIT over one 64l x 64co tile; LDS cross-wave reduction;
// wave w finalizes m-half w. Grid: CT*256, g=bid&255 -> A-sharers same XCD.
// MODE 0: relu -> bf16 octet-planar out. MODE 1: energy epilogue + LN stats.
template <int WOCT, int IOCT, int OOCT, int COD, int MODE, bool SPLIT>
__global__ __launch_bounds__(128) void mfma_conv(
    const short* __restrict__ inh, const short* __restrict__ inl,
    const short* __restrict__ wh, const short* __restrict__ wl,
    const float* __restrict__ part_in, float* __restrict__ part_out,
    short* __restrict__ outh, short* __restrict__ outl) {
    constexpr int SL = WOCT / 2;        // K16 slices total
    constexpr int KB = SL / 2;          // slices per wave
    constexpr int NIT = KB * 3;         // (slice, tap) iterations per wave
    int bid = blockIdx.x;
    int g = bid & 255;
    int ct = bid >> 8;
    int b = g >> 3, lt = g & 7;
    int l0 = lt * 64;
    int tid = threadIdx.x;
    int lane = tid & 63;
    int w = __builtin_amdgcn_readfirstlane(tid >> 6);  // K-half / m-half
    int lane31 = lane & 31, lhalf = lane >> 5;
    int co0 = ct * 64;
    const size_t ibase = (size_t)b * IOCT * RP;

    f32x16 acc[2][2];
    #pragma unroll
    for (int i = 0; i < 2; i++)
        #pragma unroll
        for (int j = 0; j < 2; j++)
            #pragma unroll
            for (int r = 0; r < 16; r++) acc[i][j][r] = 0.f;

    // running (slice, tap) cursor — wave-uniform (SGPR)
    int s = w * KB, tap = 0;
    const size_t arow0 = ibase + (size_t)lhalf * RP + (l0 + lane31) * 8;
    const size_t brow0 = ((size_t)lhalf * COD + co0 + lane31) * 8;

    auto loadf = [&](bf16x8* A, bf16x8* AL, bf16x8* B, bf16x8* BL) {
        size_t ao = arow0 + (size_t)(2 * s) * RP + tap * 8;
        A[0] = *(const bf16x8*)(inh + ao);
        A[1] = *(const bf16x8*)(inh + ao + 32 * 8);
        if (SPLIT) {
            AL[0] = *(const bf16x8*)(inl + ao);
            AL[1] = *(const bf16x8*)(inl + ao + 32 * 8);
        }
        size_t bo = brow0 + (size_t)(tap * WOCT + 2 * s) * (COD * 8);
        B[0] = *(const bf16x8*)(wh + bo);
        B[1] = *(const bf16x8*)(wh + bo + 32 * 8);
        if (SPLIT) {
            BL[0] = *(const bf16x8*)(wl + bo);
            BL[1] = *(const bf16x8*)(wl + bo + 32 * 8);
        }
        tap++;
        if (tap == 3) { tap = 0; s++; }
    };
    auto domfma = [&](bf16x8* A, bf16x8* AL, bf16x8* B, bf16x8* BL) {
        #pragma unroll
        for (int mt = 0; mt < 2; mt++)
            #pragma unroll
            for (int nt = 0; nt < 2; nt++) {
                acc[mt][nt] = __builtin_amdgcn_mfma_f32_32x32x16_bf16(
                    A[mt], B[nt], acc[mt][nt], 0, 0, 0);
                if (SPLIT) {
                    acc[mt][nt] = __builtin_amdgcn_mfma_f32_32x32x16_bf16(
                        A[mt], BL[nt], acc[mt][nt], 0, 0, 0);
                    acc[mt][nt] = __builtin_amdgcn_mfma_f32_32x32x16_bf16(
                        AL[mt], B[nt], acc[mt][nt], 0, 0, 0);
                }
            }
    };

    bf16x8 A0[2], AL0[2], B0[2], BL0[2];
    bf16x8 A1[2], AL1[2], B1[2], BL1[2];
    loadf(A0, AL0, B0, BL0);
    if (NIT & 1) {
        #pragma unroll 1
        for (int p = 0; p < NIT / 2; p++) {
            loadf(A1, AL1, B1, BL1);
            domfma(A0, AL0, B0, BL0);
            loadf(A0, AL0, B0, BL0);
            domfma(A1, AL1, B1, BL1);
        }
        domfma(A0, AL0, B0, BL0);
    } else {
        #pragma unroll 1
        for (int p = 0; p < NIT / 2 - 1; p++) {
            loadf(A1, AL1, B1, BL1);
            domfma(A0, AL0, B0, BL0);
            loadf(A0, AL0, B0, BL0);
            domfma(A1, AL1, B1, BL1);
        }
        loadf(A1, AL1, B1, BL1);
        domfma(A0, AL0, B0, BL0);
        domfma(A1, AL1, B1, BL1);
    }

    // ---- cross-wave K reduction (stride 33 f32: conflict-free)
    constexpr int RSTR = 33;
    __shared__ float red[2 * 64 * RSTR];
    {
        float* my = &red[w * 64 * RSTR + lane * RSTR];
        int src = 1 - w;  // export the m-half this wave does NOT finalize
        #pragma unroll
        for (int nt = 0; nt < 2; nt++)
            #pragma unroll
            for (int r = 0; r < 16; r++) my[nt * 16 + r] = acc[src][nt][r];
    }
    __syncthreads();
    {
        const float* pr = &red[(1 - w) * 64 * RSTR + lane * RSTR];
        #pragma unroll
        for (int nt = 0; nt < 2; nt++)
            #pragma unroll
            for (int r = 0; r < 16; r++) acc[w][nt][r] += pr[nt * 16 + r];
    }

    // C/D mapping (32x32): col = lane&31, row = (r&3) + 8*(r>>2) + 4*(lane>>5)
    const size_t obase = (size_t)b * OOCT * RP;
    if (MODE == 1) {
        float s_in = part_in[b * 2], sq_in = part_in[b * 2 + 1];
        float mu = s_in / (float)NPB;
        float var = sq_in / (float)NPB - mu * mu;
        float rs = rsqrtf(var + 1e-5f);
        float ss = 0.f, sq = 0.f;
        #pragma unroll
        for (int nt = 0; nt < 2; nt++)
            #pragma unroll
            for (int r = 0; r < 16; r++) {
                int m = w * 32 + (r & 3) + 8 * (r >> 2) + 4 * lhalf;
                int n = co0 + nt * 32 + lane31;
                size_t idx = ibase + (size_t)(n >> 3) * RP +
                             (l0 + m + 1) * 8 + (n & 7);
                float itv = b2f(inh[idx]) + b2f(inl[idx]);
                float xl = (itv - mu) * rs;
                float nv = xl - 0.1f * acc[w][nt][r] - 0.2f * fmaxf(xl, 0.f);
                ss += nv;
                sq += nv * nv;
                __hip_bfloat16 h = __float2bfloat16(nv);
                outh[idx] = *(short*)&h;
                outl[idx] = f2b(nv - __bfloat162float(h));
            }
        #pragma unroll
        for (int off = 32; off > 0; off >>= 1) {
            ss += __shfl_down(ss, off);
            sq += __shfl_down(sq, off);
        }
        __shared__ float sr[4];
        if (lane == 0) { sr[w] = ss; sr[2 + w] = sq; }
        __syncthreads();
        if (tid == 0) {
            atomicAdd(&part_out[b * 2], sr[0] + sr[1]);
            atomicAdd(&part_out[b * 2 + 1], sr[2] + sr[3]);
        }
    } else {
        #pragma unroll
        for (int nt = 0; nt < 2; nt++)
            #pragma unroll
            for (int r = 0; r < 16; r++) {
                int m = w * 32 + (r & 3) + 8 * (r >> 2) + 4 * lhalf;
                int n = co0 + nt * 32 + lane31;
                size_t idx = obase + (size_t)(n >> 3) * RP +
                             (l0 + m + 1) * 8 + (n & 7);
                outh[idx] = f2b(fmaxf(acc[w][nt][r], 0.f));
            }
    }
}

// Final 192->2 conv from a2 [32][32oct][514][8] bf16 octet-planar.
__global__ __launch_bounds__(128) void h3_conv(const short* __restrict__ a2,
                                               const float* __restrict__ w3,
                                               float* __restrict__ out, int t) {
    __shared__ float ws3[2 * 192 * 3];
    int tid = threadIdx.x;
    for (int i = tid; i < 2 * 192 * 3; i += 128) ws3[i] = w3[i];
    __syncthreads();
    int b = blockIdx.x >> 3, sl = blockIdx.x & 7;
    int l = sl * 64 + (tid >> 1);
    int ch = tid & 1;
    const short* ab = a2 + (size_t)b * 32 * RP;
    const float* wc = ws3 + ch * 576;
    float a = 0.f;
    #pragma unroll 4
    for (int oct = 0; oct < 24; oct++) {
        const short* p = ab + (size_t)oct * RP + l * 8;  // row l = seq l-1
        bf16x8 v0 = *(const bf16x8*)p;
        bf16x8 v1 = *(const bf16x8*)(p + 8);
        bf16x8 v2 = *(const bf16x8*)(p + 16);
        #pragma unroll
        for (int j = 0; j < 8; j++) {
            const float* wp = wc + (oct * 8 + j) * 3;
            a += wp[0] * b2f(v0[j]) + wp[1] * b2f(v1[j]) + wp[2] * b2f(v2[j]);
        }
    }
    out[(((size_t)b * ITERS + t) * 2 + ch) * LL + l] = a;
}

extern "C" void kernel_launch(void* const* d_in, const int* in_sizes, int n_in,
                              void* d_out, int out_size, void* d_ws, size_t ws_size,
                              hipStream_t stream) {
    const float* x = (const float*)d_in[0];
    const float* proj_w = (const float*)d_in[2];
    const float* op_w = (const float*)d_in[3];
    const float* h1_w = (const float*)d_in[4];
    const float* h2_w = (const float*)d_in[5];
    const float* h3_w = (const float*)d_in[6];
    float* out = (float*)d_out;

    char* base = (char*)d_ws;
    size_t off = 0;
    auto alloc = [&](size_t bytes) {
        char* p = base + off;
        off += (bytes + 255) & ~(size_t)255;
        return p;
    };
    const size_t ITB = (size_t)BB * 52 * RP * 2;  // state buffer bytes
    short* itAh = (short*)alloc(ITB);
    short* itAl = (short*)alloc(ITB);
    short* itBh = (short*)alloc(ITB);
    short* itBl = (short*)alloc(ITB);
    short* a1 = (short*)alloc((size_t)BB * 48 * RP * 2);
    short* a2 = (short*)alloc((size_t)BB * 32 * RP * 2);
    short* wOph = (short*)alloc((size_t)3 * 52 * 384 * 8 * 2);
    short* wOpl = (short*)alloc((size_t)3 * 52 * 384 * 8 * 2);
    short* wH1 = (short*)alloc((size_t)3 * 48 * 384 * 8 * 2);
    short* wH2 = (short*)alloc((size_t)3 * 48 * 256 * 8 * 2);
    float* part = (float*)alloc((size_t)(ITERS + 1) * 64 * 4);
    if (off > ws_size) return;

    wsplit_op<<<(3 * 52 * 384 * 8 + 255) / 256, 256, 0, stream>>>(op_w, wOph, wOpl);
    wsplit_h<<<(3 * 48 * 384 * 8 + 255) / 256, 256, 0, stream>>>(h1_w, wH1, 384, 384);
    wsplit_h<<<(3 * 48 * 256 * 8 + 255) / 256, 256, 0, stream>>>(h2_w, wH2, 256, 192);
    init_rows<<<BB * LROWS, 64, 0, stream>>>(x, itAh, itAl, itBh, itBl, a1, a2);
    zero_part<<<5, 256, 0, stream>>>(part, (ITERS + 1) * 64);
    proj_relu<<<BB * 8, 256, 0, stream>>>(x, proj_w, itAh, itAl, part);

    short *ch = itAh, *cl = itAl, *nh = itBh, *nl = itBl;
    for (int t = 0; t < ITERS; t++) {
        // op conv (hi/lo split, energy epilogue): cur -> nxt, stats -> part[t+1]
        mfma_conv<52, 52, 52, 384, 1, true><<<6 * 256, 128, 0, stream>>>(
            ch, cl, wOph, wOpl, part + t * 64, part + (t + 1) * 64, nh, nl);
        // h1: nxt_hi -> a1 (48 octets), relu
        mfma_conv<48, 52, 48, 384, 0, false><<<6 * 256, 128, 0, stream>>>(
            nh, nullptr, wH1, nullptr, nullptr, nullptr, a1, nullptr);
        // h2: a1 -> a2 (co padded to 256 -> 32 octets), relu
        mfma_conv<48, 48, 32, 256, 0, false><<<4 * 256, 128, 0, stream>>>(
            a1, nullptr, wH2, nullptr, nullptr, nullptr, a2, nullptr);
        h3_conv<<<BB * 8, 128, 0, stream>>>(a2, h3_w, out, t);
        short* th = ch; ch = nh; nh = th;
        short* tl = cl; cl = nl; nl = tl;
    }
}

// Round 9
// 1916.542 us; speedup vs baseline: 1.5638x; 1.5000x over previous
//
#include <hip/hip_runtime.h>
#include <hip/hip_bf16.h>

#define BB 32
#define WW 384
#define LL 512
#define ITERS 16
#define NPB (WW * LL)
#define LROWS 514            // 1 + 512 + 1 halo rows
#define RP (LROWS * 8)       // shorts per octet-plane (4112)

typedef __attribute__((ext_vector_type(8))) short bf16x8;
typedef __attribute__((ext_vector_type(4))) float f32x4;

__device__ __forceinline__ float b2f(short s) {
    unsigned u = ((unsigned)(unsigned short)s) << 16;
    float f;
    __builtin_memcpy(&f, &u, 4);
    return f;
}
__device__ __forceinline__ short f2b(float v) {
    __hip_bfloat16 h = __float2bfloat16(v);
    return *(short*)&h;
}

// ---------------------------------------------------------------- prep
// op_w [384(co)][385(ci)][3] f32 -> Wh/Wl [3][52][384][8] bf16 hi/lo
__global__ void wsplit_op(const float* __restrict__ w, short* __restrict__ wh,
                          short* __restrict__ wl) {
    int i = blockIdx.x * 256 + threadIdx.x;
    if (i >= 3 * 52 * 384 * 8) return;
    int e = i & 7, co = (i >> 3) % 384, oct = (i >> 3) / 384 % 52,
        tap = i / (8 * 384 * 52);
    int ci = oct * 8 + e;
    float v = (ci < 385) ? w[(co * 385 + ci) * 3 + tap] : 0.f;
    __hip_bfloat16 h = __float2bfloat16(v);
    wh[i] = *(short*)&h;
    wl[i] = f2b(v - __bfloat162float(h));
}

// src [CO_real][384(ci)][3] f32 -> dst [3][48][COD][8] bf16 (co>=CO_real -> 0)
__global__ void wsplit_h(const float* __restrict__ w, short* __restrict__ wh,
                         int COD, int CO_real) {
    int i = blockIdx.x * 256 + threadIdx.x;
    if (i >= 3 * 48 * COD * 8) return;
    int e = i & 7, co = (i >> 3) % COD, oct = (i >> 3) / COD % 48,
        tap = i / (8 * COD * 48);
    int ci = oct * 8 + e;
    float v = (co < CO_real) ? w[(co * 384 + ci) * 3 + tap] : 0.f;
    wh[i] = f2b(v);
}

// Zero halo rows (all buffers), install x channel (octet 48, elem 0) + zero
// pad octets 48..51 in both state ping-pong buffers.
__global__ void init_rows(const float* __restrict__ x, short* itAh, short* itAl,
                          short* itBh, short* itBl, short* a1, short* a2A,
                          short* a2B) {
    int row = blockIdx.x % LROWS, b = blockIdx.x / LROWS;
    int tid = threadIdx.x;
    size_t sb = (size_t)b * 52 * RP;
    if (row == 0 || row == LROWS - 1) {
        for (int i = tid; i < 52 * 8; i += 64) {
            size_t o = sb + (size_t)(i >> 3) * RP + row * 8 + (i & 7);
            itAh[o] = 0; itAl[o] = 0; itBh[o] = 0; itBl[o] = 0;
        }
        for (int i = tid; i < 48 * 8; i += 64)
            a1[(size_t)b * 48 * RP + (size_t)(i >> 3) * RP + row * 8 + (i & 7)] = 0;
        for (int i = tid; i < 32 * 8; i += 64) {
            size_t o = (size_t)b * 32 * RP + (size_t)(i >> 3) * RP + row * 8 + (i & 7);
            a2A[o] = 0; a2B[o] = 0;
        }
    } else if (tid < 32) {
        int oct = 48 + (tid >> 3), e = tid & 7;
        short h = 0, l = 0;
        if (oct == 48 && e == 0) {
            float xv = x[b * LL + row - 1];
            __hip_bfloat16 xh = __float2bfloat16(xv);
            h = *(short*)&xh;
            l = f2b(xv - __bfloat162float(xh));
        }
        size_t o = sb + (size_t)oct * RP + row * 8 + e;
        itAh[o] = h; itAl[o] = l; itBh[o] = h; itBl[o] = l;
    }
}

__global__ void zero_part(float* part, int n) {
    int i = blockIdx.x * 256 + threadIdx.x;
    if (i < n) part[i] = 0.f;
}

// it0 = relu(conv1d(x, proj_w)) -> octet-planar hi/lo + LN stats.
__global__ __launch_bounds__(256) void proj_relu(const float* __restrict__ x,
                                                 const float* __restrict__ wp,
                                                 short* __restrict__ oh,
                                                 short* __restrict__ ol,
                                                 float* __restrict__ part) {
    int b = blockIdx.x >> 3, sl = blockIdx.x & 7;
    int tid = threadIdx.x;
    __shared__ float ws[WW * 3];
    __shared__ float xs[66];
    for (int i = tid; i < WW * 3; i += 256) ws[i] = wp[i];
    int l0 = sl * 64;
    for (int i = tid; i < 66; i += 256) {
        int l = l0 + i - 1;
        xs[i] = (l >= 0 && l < LL) ? x[b * LL + l] : 0.f;
    }
    __syncthreads();
    size_t sb = (size_t)b * 52 * RP;
    float s = 0.f, sq = 0.f;
    for (int idx = tid; idx < 64 * WW; idx += 256) {
        int lo = idx / WW, co = idx % WW;
        float v = fmaxf(ws[co * 3] * xs[lo] + ws[co * 3 + 1] * xs[lo + 1] +
                            ws[co * 3 + 2] * xs[lo + 2], 0.f);
        size_t o = sb + (size_t)(co >> 3) * RP + (l0 + lo + 1) * 8 + (co & 7);
        __hip_bfloat16 h = __float2bfloat16(v);
        oh[o] = *(short*)&h;
        ol[o] = f2b(v - __bfloat162float(h));
        s += v; sq += v * v;
    }
    #pragma unroll
    for (int off = 32; off > 0; off >>= 1) {
        s += __shfl_down(s, off);
        sq += __shfl_down(sq, off);
    }
    __shared__ float sr[8];
    int w = tid >> 6;
    if ((tid & 63) == 0) { sr[w] = s; sr[4 + w] = sq; }
    __syncthreads();
    if (tid == 0) {
        atomicAdd(&part[b * 2], sr[0] + sr[1] + sr[2] + sr[3]);
        atomicAdd(&part[b * 2 + 1], sr[4] + sr[5] + sr[6] + sr[7]);
    }
}

// ------------------------------------------------- MFMA implicit-GEMM conv
// Round-6 proven body (no spills): direct-global octet-planar loads
// (contiguous 256B/16-lane), no LDS staging, no K-loop barriers.
// Block: 2 waves splitting co; wave tile 64l x 64co (4x4 16x16x32 MFMA).
// bid layout: g=bid&255 (b*8+lt), ct=bid>>8 -> A-sharers on same XCD.
// MODE 0: relu -> bf16 octet-planar out. MODE 1: energy epilogue + LN stats.
template <int CHUNKS, int IOCT, int OOCT, int COD, int MODE, bool SPLIT>
__device__ __forceinline__ void conv_body(
    int bid, const short* __restrict__ inh, const short* __restrict__ inl,
    const short* __restrict__ wh, const short* __restrict__ wl,
    const float* __restrict__ part_in, float* __restrict__ part_out,
    short* __restrict__ outh, short* __restrict__ outl) {
    int g = bid & 255;
    int ct = bid >> 8;
    int b = g >> 3, lt = g & 7;
    int l0 = lt * 64;
    int tid = threadIdx.x;
    int lane = tid & 63;
    int wn = __builtin_amdgcn_readfirstlane(tid >> 6);
    int lane15 = lane & 15, q = lane >> 4;
    int co0 = ct * 128 + wn * 64;
    const size_t ibase = (size_t)b * IOCT * RP;

    f32x4 acc[4][4];
    #pragma unroll
    for (int i = 0; i < 4; i++)
        #pragma unroll
        for (int j = 0; j < 4; j++) acc[i][j] = (f32x4){0.f, 0.f, 0.f, 0.f};

    const size_t arow = ibase + (size_t)q * RP + (l0 + lane15) * 8;
    const size_t brow = ((size_t)q * COD + co0 + lane15) * 8;

    #pragma unroll 1
    for (int kc = 0; kc < CHUNKS; kc++) {
        #pragma unroll
        for (int tap = 0; tap < 3; tap++) {
            bf16x8 ah[4], al[4], bh[4], bl[4];
            #pragma unroll
            for (int mt = 0; mt < 4; mt++) {
                size_t ao = arow + (size_t)kc * 4 * RP + (mt * 16 + tap) * 8;
                ah[mt] = *(const bf16x8*)(inh + ao);
                if (SPLIT) al[mt] = *(const bf16x8*)(inl + ao);
            }
            #pragma unroll
            for (int nt = 0; nt < 4; nt++) {
                size_t bo = brow + ((size_t)(tap * CHUNKS + kc) * 4) * COD * 8 +
                            nt * 16 * 8;
                bh[nt] = *(const bf16x8*)(wh + bo);
                if (SPLIT) bl[nt] = *(const bf16x8*)(wl + bo);
            }
            #pragma unroll
            for (int mt = 0; mt < 4; mt++)
                #pragma unroll
                for (int nt = 0; nt < 4; nt++) {
                    acc[mt][nt] = __builtin_amdgcn_mfma_f32_16x16x32_bf16(
                        ah[mt], bh[nt], acc[mt][nt], 0, 0, 0);
                    if (SPLIT) {
                        acc[mt][nt] = __builtin_amdgcn_mfma_f32_16x16x32_bf16(
                            ah[mt], bl[nt], acc[mt][nt], 0, 0, 0);
                        acc[mt][nt] = __builtin_amdgcn_mfma_f32_16x16x32_bf16(
                            al[mt], bh[nt], acc[mt][nt], 0, 0, 0);
                    }
                }
        }
    }

    const size_t obase = (size_t)b * OOCT * RP;
    if (MODE == 1) {
        float s_in = part_in[b * 2], sq_in = part_in[b * 2 + 1];
        float mu = s_in / (float)NPB;
        float var = sq_in / (float)NPB - mu * mu;
        float rs = rsqrtf(var + 1e-5f);
        float s = 0.f, sq = 0.f;
        #pragma unroll
        for (int mt = 0; mt < 4; mt++)
            #pragma unroll
            for (int nt = 0; nt < 4; nt++)
                #pragma unroll
                for (int r = 0; r < 4; r++) {
                    int m = mt * 16 + q * 4 + r;
                    int n = co0 + nt * 16 + lane15;
                    size_t idx = ibase + (size_t)(n >> 3) * RP +
                                 (l0 + m + 1) * 8 + (n & 7);
                    float itv = b2f(inh[idx]) + b2f(inl[idx]);
                    float xl = (itv - mu) * rs;
                    float nv = xl - 0.1f * acc[mt][nt][r] - 0.2f * fmaxf(xl, 0.f);
                    s += nv;
                    sq += nv * nv;
                    __hip_bfloat16 h = __float2bfloat16(nv);
                    outh[idx] = *(short*)&h;
                    outl[idx] = f2b(nv - __bfloat162float(h));
                }
        #pragma unroll
        for (int off = 32; off > 0; off >>= 1) {
            s += __shfl_down(s, off);
            sq += __shfl_down(sq, off);
        }
        __shared__ float sr[4];
        int w = tid >> 6;
        if (lane == 0) { sr[w] = s; sr[2 + w] = sq; }
        __syncthreads();
        if (tid == 0) {
            atomicAdd(&part_out[b * 2], sr[0] + sr[1]);
            atomicAdd(&part_out[b * 2 + 1], sr[2] + sr[3]);
        }
    } else {
        #pragma unroll
        for (int mt = 0; mt < 4; mt++)
            #pragma unroll
            for (int nt = 0; nt < 4; nt++)
                #pragma unroll
                for (int r = 0; r < 4; r++) {
                    int m = mt * 16 + q * 4 + r;
                    int n = co0 + nt * 16 + lane15;
                    size_t idx = obase + (size_t)(n >> 3) * RP +
                                 (l0 + m + 1) * 8 + (n & 7);
                    outh[idx] = f2b(fmaxf(acc[mt][nt][r], 0.f));
                }
    }
}

// Final 192->2 conv body from a2 [32][32oct][514][8] bf16 octet-planar.
__device__ __forceinline__ void h3_body(int bid, const short* __restrict__ a2,
                                        const float* __restrict__ w3,
                                        float* __restrict__ out, int t) {
    __shared__ float ws3[2 * 192 * 3];
    int tid = threadIdx.x;
    for (int i = tid; i < 2 * 192 * 3; i += 128) ws3[i] = w3[i];
    __syncthreads();
    int b = bid >> 3, sl = bid & 7;
    int l = sl * 64 + (tid >> 1);
    int ch = tid & 1;
    const short* ab = a2 + (size_t)b * 32 * RP;
    const float* wc = ws3 + ch * 576;
    float a = 0.f;
    #pragma unroll 4
    for (int oct = 0; oct < 24; oct++) {
        const short* p = ab + (size_t)oct * RP + l * 8;  // row l = seq l-1
        bf16x8 v0 = *(const bf16x8*)p;
        bf16x8 v1 = *(const bf16x8*)(p + 8);
        bf16x8 v2 = *(const bf16x8*)(p + 16);
        #pragma unroll
        for (int j = 0; j < 8; j++) {
            const float* wp = wc + (oct * 8 + j) * 3;
            a += wp[0] * b2f(v0[j]) + wp[1] * b2f(v1[j]) + wp[2] * b2f(v2[j]);
        }
    }
    out[(((size_t)b * ITERS + t) * 2 + ch) * LL + l] = a;
}

// F(t): op(t) [blocks 0..opBlocks) || h1(t-1) [blocks opBlocks..). Both only
// READ cur (ch/cl); op writes nxt, h1 writes a1 — no intra-launch ordering.
__global__ __launch_bounds__(128) void fusedF(
    const short* __restrict__ ch, const short* __restrict__ cl,
    short* __restrict__ nh, short* __restrict__ nl,
    const short* __restrict__ wOph, const short* __restrict__ wOpl,
    const short* __restrict__ wH1, const float* __restrict__ part_in,
    float* __restrict__ part_out, short* __restrict__ a1, int opBlocks) {
    int bid = blockIdx.x;
    if (bid < opBlocks) {
        conv_body<13, 52, 52, 384, 1, true>(bid, ch, cl, wOph, wOpl, part_in,
                                            part_out, nh, nl);
    } else {
        conv_body<12, 52, 48, 384, 0, false>(bid - opBlocks, ch, nullptr, wH1,
                                             nullptr, nullptr, nullptr, a1,
                                             nullptr);
    }
}

// G(t): h2(t-1) [blocks 0..h2Blocks) || h3(t-2) [rest] (a2 ping-pong).
__global__ __launch_bounds__(128) void fusedG(
    const short* __restrict__ a1, const short* __restrict__ wH2,
    short* __restrict__ a2w, const short* __restrict__ a2r,
    const float* __restrict__ w3, float* __restrict__ out, int t3,
    int h2Blocks) {
    int bid = blockIdx.x;
    if (bid < h2Blocks) {
        conv_body<12, 48, 32, 256, 0, false>(bid, a1, nullptr, wH2, nullptr,
                                             nullptr, nullptr, a2w, nullptr);
    } else {
        h3_body(bid - h2Blocks, a2r, w3, out, t3);
    }
}

extern "C" void kernel_launch(void* const* d_in, const int* in_sizes, int n_in,
                              void* d_out, int out_size, void* d_ws, size_t ws_size,
                              hipStream_t stream) {
    const float* x = (const float*)d_in[0];
    const float* proj_w = (const float*)d_in[2];
    const float* op_w = (const float*)d_in[3];
    const float* h1_w = (const float*)d_in[4];
    const float* h2_w = (const float*)d_in[5];
    const float* h3_w = (const float*)d_in[6];
    float* out = (float*)d_out;

    char* base = (char*)d_ws;
    size_t off = 0;
    auto alloc = [&](size_t bytes) {
        char* p = base + off;
        off += (bytes + 255) & ~(size_t)255;
        return p;
    };
    const size_t ITB = (size_t)BB * 52 * RP * 2;  // state buffer bytes
    short* itAh = (short*)alloc(ITB);
    short* itAl = (short*)alloc(ITB);
    short* itBh = (short*)alloc(ITB);
    short* itBl = (short*)alloc(ITB);
    short* a1 = (short*)alloc((size_t)BB * 48 * RP * 2);
    short* a2A = (short*)alloc((size_t)BB * 32 * RP * 2);
    short* a2B = (short*)alloc((size_t)BB * 32 * RP * 2);
    short* wOph = (short*)alloc((size_t)3 * 52 * 384 * 8 * 2);
    short* wOpl = (short*)alloc((size_t)3 * 52 * 384 * 8 * 2);
    short* wH1 = (short*)alloc((size_t)3 * 48 * 384 * 8 * 2);
    short* wH2 = (short*)alloc((size_t)3 * 48 * 256 * 8 * 2);
    float* part = (float*)alloc((size_t)(ITERS + 1) * 64 * 4);
    if (off > ws_size) return;

    wsplit_op<<<(3 * 52 * 384 * 8 + 255) / 256, 256, 0, stream>>>(op_w, wOph, wOpl);
    wsplit_h<<<(3 * 48 * 384 * 8 + 255) / 256, 256, 0, stream>>>(h1_w, wH1, 384, 384);
    wsplit_h<<<(3 * 48 * 256 * 8 + 255) / 256, 256, 0, stream>>>(h2_w, wH2, 256, 192);
    init_rows<<<BB * LROWS, 64, 0, stream>>>(x, itAh, itAl, itBh, itBl, a1, a2A, a2B);
    zero_part<<<5, 256, 0, stream>>>(part, (ITERS + 1) * 64);
    proj_relu<<<BB * 8, 256, 0, stream>>>(x, proj_w, itAh, itAl, part);

    short* a2buf[2] = {a2A, a2B};
    short *ch = itAh, *cl = itAl, *nh = itBh, *nl = itBl;
    for (int t = 0; t < ITERS; t++) {
        int h1B = (t > 0) ? 768 : 0;
        // F(t): op(t) (cur->nxt, stats part[t]->part[t+1]) || h1(t-1) (cur->a1)
        fusedF<<<768 + h1B, 128, 0, stream>>>(ch, cl, nh, nl, wOph, wOpl, wH1,
                                              part + t * 64, part + (t + 1) * 64,
                                              a1, 768);
        // G(t): h2(t-1) (a1->a2[(t-1)&1]) || h3(t-2) (a2[(t-2)&1]->out[t-2])
        if (t > 0) {
            int h3B = (t > 1) ? 256 : 0;
            fusedG<<<512 + h3B, 128, 0, stream>>>(
                a1, wH2, a2buf[(t - 1) & 1], (t > 1) ? a2buf[(t - 2) & 1] : a2A,
                h3_w, out, t - 2, 512);
        }
        short* th = ch; ch = nh; nh = th;
        short* tl = cl; cl = nl; nl = tl;
    }
    // Tail: h1(15) reads final state; then h2(15) || h3(14); then h3(15).
    fusedF<<<768, 128, 0, stream>>>(ch, cl, nh, nl, wOph, wOpl, wH1, nullptr,
                                    nullptr, a1, 0);
    fusedG<<<512 + 256, 128, 0, stream>>>(a1, wH2, a2buf[(ITERS - 1) & 1],
                                          a2buf[(ITERS - 2) & 1], h3_w, out,
                                          ITERS - 2, 512);
    fusedG<<<256, 128, 0, stream>>>(a1, wH2, a2A, a2buf[(ITERS - 1) & 1], h3_w,
                                    out, ITERS - 1, 0);
}